// Round 11
// baseline (439.107 us; speedup 1.0000x reference)
//
#include <hip/hip_runtime.h>
#include <hip/hip_bf16.h>

#define NV 100000
#define NE 25000
#define NNZ_ 1600000
#define CH 256
#define ESTRIDE 128   // max edge degree (Poisson λ=64, +8σ)
#define VSTRIDE 48    // max vertex degree (Poisson λ=16, +8σ)
#define LDSK 264      // 256 + 8 u16 pad -> 528B row stride

typedef unsigned int u32;
typedef unsigned short u16;
typedef __attribute__((ext_vector_type(8))) short bf16x8;
typedef __attribute__((ext_vector_type(4))) float f32x4;

__device__ __forceinline__ float bf2f(u16 u){ return __uint_as_float(((u32)u)<<16); }
__device__ __forceinline__ u16 f2bf(float f){ __hip_bfloat16 h = __float2bfloat16(f); return *reinterpret_cast<u16*>(&h); }
__device__ __forceinline__ void acc4(float4& a, ushort4 u){
  a.x += bf2f(u.x); a.y += bf2f(u.y); a.z += bf2f(u.z); a.w += bf2f(u.w);
}

// ---- 1. fused padded-CSR build ----
__global__ void k_build(const int* __restrict__ v_idx, const int* __restrict__ e_idx,
                        int* __restrict__ dv_cnt, int* __restrict__ de_cnt,
                        u16* __restrict__ v_listP, int* __restrict__ e_listP){
  int part = blockIdx.x & 7;
  int grp  = blockIdx.x >> 3;
  int ngrp = gridDim.x >> 3;
  int eLo = part*(NE/8), eHi = eLo + (NE/8);
  int vLo = part*(NV/8), vHi = vLo + (NV/8);
  int i = grp*blockDim.x + threadIdx.x;
  int stride = ngrp*blockDim.x;
  for (; i<NNZ_; i+=stride){
    int v = __builtin_nontemporal_load(&v_idx[i]);
    int e = __builtin_nontemporal_load(&e_idx[i]);
    if (e>=eLo && e<eHi){ int s = atomicAdd(&de_cnt[e],1); e_listP[(e<<7)+s] = v; }
    if (v>=vLo && v<vHi){ int s = atomicAdd(&dv_cnt[v],1); v_listP[v*VSTRIDE+s] = (u16)e; }
  }
}

// ---- 2. dv^-1/2 ----
__global__ void k_dvis(const int* __restrict__ dv_cnt, float* __restrict__ dv_isqrt){
  int v = blockIdx.x*blockDim.x + threadIdx.x;
  if (v < NV){ int d = dv_cnt[v]; dv_isqrt[v] = d>0 ? rsqrtf((float)d) : 0.f; }
}

// ---- 3. Xs = dv_isqrt * X, cast to bf16 ----
__global__ void k_xs(const float4* __restrict__ X4, const float* __restrict__ dv_isqrt,
                     ushort4* __restrict__ Xs4){
  int i = blockIdx.x*blockDim.x + threadIdx.x;
  int v = i >> 6;
  float w = dv_isqrt[v];
  float4 x = X4[i];
  ushort4 o;
  o.x = f2bf(x.x*w); o.y = f2bf(x.y*w); o.z = f2bf(x.z*w); o.w = f2bf(x.w*w);
  Xs4[i] = o;
}

// ---- 4. Wh[n][k] = bf16(W[k][n]) ----
__global__ void k_wh(const float* __restrict__ W, u16* __restrict__ Wh){
  __shared__ float tile[16][17];
  int bx=blockIdx.x, by=blockIdx.y;
  int tx=threadIdx.x, ty=threadIdx.y;
  tile[ty][tx] = W[(by*16+ty)*256 + bx*16+tx];
  __syncthreads();
  Wh[(bx*16+ty)*256 + by*16+tx] = f2bf(tile[tx][ty]);
}

// ---- 5. fused: gather 16-edge tile (2 rows/wave interleaved, 16-deep MLP)
//      -> LDS bf16 -> MFMA @ Wh -> Ue bf16 (+tb) ----
__global__ __launch_bounds__(256) void k_tegemm(const int* __restrict__ de_cnt,
                     const int* __restrict__ e_listP, const ushort4* __restrict__ Xs4,
                     const float* __restrict__ dv_isqrt, const u16* __restrict__ Wh,
                     float* __restrict__ tb, u16* __restrict__ Ue){
  __shared__ u16 lds[16][LDSK];
  int t = threadIdx.x, w = t>>6, lane = t&63;
  int e0 = blockIdx.x*16;
  const float4 z = make_float4(0,0,0,0);

  for (int j=0;j<2;++j){
    int rA = w*4 + j*2, rB = rA + 1;
    int eA = e0 + rA, eB = e0 + rB;
    float4 a0=z, a1=z, c0=z, c1=z;
    float tsA=0.f, tsB=0.f;
    int degA = (eA<NE) ? de_cnt[eA] : 0;
    int degB = (eB<NE) ? de_cnt[eB] : 0;
    int baseA = eA<<7, baseB = eB<<7;
    int mc = min(degA, degB);
    int m = 0;
    // interleaved: 8-deep per row x 2 rows = 16 concurrent 512B gathers
    for (; m+8 <= mc; m += 8){
      int va0=e_listP[baseA+m+0], va1=e_listP[baseA+m+1], va2=e_listP[baseA+m+2], va3=e_listP[baseA+m+3];
      int va4=e_listP[baseA+m+4], va5=e_listP[baseA+m+5], va6=e_listP[baseA+m+6], va7=e_listP[baseA+m+7];
      int vb0=e_listP[baseB+m+0], vb1=e_listP[baseB+m+1], vb2=e_listP[baseB+m+2], vb3=e_listP[baseB+m+3];
      int vb4=e_listP[baseB+m+4], vb5=e_listP[baseB+m+5], vb6=e_listP[baseB+m+6], vb7=e_listP[baseB+m+7];
      ushort4 uA0=Xs4[(va0<<6)+lane], uA1=Xs4[(va1<<6)+lane], uA2=Xs4[(va2<<6)+lane], uA3=Xs4[(va3<<6)+lane];
      ushort4 uA4=Xs4[(va4<<6)+lane], uA5=Xs4[(va5<<6)+lane], uA6=Xs4[(va6<<6)+lane], uA7=Xs4[(va7<<6)+lane];
      ushort4 uB0=Xs4[(vb0<<6)+lane], uB1=Xs4[(vb1<<6)+lane], uB2=Xs4[(vb2<<6)+lane], uB3=Xs4[(vb3<<6)+lane];
      ushort4 uB4=Xs4[(vb4<<6)+lane], uB5=Xs4[(vb5<<6)+lane], uB6=Xs4[(vb6<<6)+lane], uB7=Xs4[(vb7<<6)+lane];
      acc4(a0,uA0); acc4(a1,uA1); acc4(a0,uA2); acc4(a1,uA3);
      acc4(a0,uA4); acc4(a1,uA5); acc4(a0,uA6); acc4(a1,uA7);
      acc4(c0,uB0); acc4(c1,uB1); acc4(c0,uB2); acc4(c1,uB3);
      acc4(c0,uB4); acc4(c1,uB5); acc4(c0,uB6); acc4(c1,uB7);
      tsA += dv_isqrt[va0]+dv_isqrt[va1]+dv_isqrt[va2]+dv_isqrt[va3]
           + dv_isqrt[va4]+dv_isqrt[va5]+dv_isqrt[va6]+dv_isqrt[va7];
      tsB += dv_isqrt[vb0]+dv_isqrt[vb1]+dv_isqrt[vb2]+dv_isqrt[vb3]
           + dv_isqrt[vb4]+dv_isqrt[vb5]+dv_isqrt[vb6]+dv_isqrt[vb7];
    }
    // tail A: 8-deep then scalar
    int mA = m;
    for (; mA+8 <= degA; mA += 8){
      int v0=e_listP[baseA+mA+0], v1=e_listP[baseA+mA+1], v2=e_listP[baseA+mA+2], v3=e_listP[baseA+mA+3];
      int v4=e_listP[baseA+mA+4], v5=e_listP[baseA+mA+5], v6=e_listP[baseA+mA+6], v7=e_listP[baseA+mA+7];
      ushort4 u0=Xs4[(v0<<6)+lane], u1=Xs4[(v1<<6)+lane], u2=Xs4[(v2<<6)+lane], u3=Xs4[(v3<<6)+lane];
      ushort4 u4=Xs4[(v4<<6)+lane], u5=Xs4[(v5<<6)+lane], u6=Xs4[(v6<<6)+lane], u7=Xs4[(v7<<6)+lane];
      acc4(a0,u0); acc4(a1,u1); acc4(a0,u2); acc4(a1,u3);
      acc4(a0,u4); acc4(a1,u5); acc4(a0,u6); acc4(a1,u7);
      tsA += dv_isqrt[v0]+dv_isqrt[v1]+dv_isqrt[v2]+dv_isqrt[v3]
           + dv_isqrt[v4]+dv_isqrt[v5]+dv_isqrt[v6]+dv_isqrt[v7];
    }
    for (; mA<degA; ++mA){
      int v = e_listP[baseA+mA];
      acc4(a0, Xs4[(v<<6)+lane]);
      tsA += dv_isqrt[v];
    }
    // tail B: 8-deep then scalar
    int mB = m;
    for (; mB+8 <= degB; mB += 8){
      int v0=e_listP[baseB+mB+0], v1=e_listP[baseB+mB+1], v2=e_listP[baseB+mB+2], v3=e_listP[baseB+mB+3];
      int v4=e_listP[baseB+mB+4], v5=e_listP[baseB+mB+5], v6=e_listP[baseB+mB+6], v7=e_listP[baseB+mB+7];
      ushort4 u0=Xs4[(v0<<6)+lane], u1=Xs4[(v1<<6)+lane], u2=Xs4[(v2<<6)+lane], u3=Xs4[(v3<<6)+lane];
      ushort4 u4=Xs4[(v4<<6)+lane], u5=Xs4[(v5<<6)+lane], u6=Xs4[(v6<<6)+lane], u7=Xs4[(v7<<6)+lane];
      acc4(c0,u0); acc4(c1,u1); acc4(c0,u2); acc4(c1,u3);
      acc4(c0,u4); acc4(c1,u5); acc4(c0,u6); acc4(c1,u7);
      tsB += dv_isqrt[v0]+dv_isqrt[v1]+dv_isqrt[v2]+dv_isqrt[v3]
           + dv_isqrt[v4]+dv_isqrt[v5]+dv_isqrt[v6]+dv_isqrt[v7];
    }
    for (; mB<degB; ++mB){
      int v = e_listP[baseB+mB];
      acc4(c0, Xs4[(v<<6)+lane]);
      tsB += dv_isqrt[v];
    }
    // finalize + stage
    float dinvA = degA>0 ? 1.f/(float)degA : 0.f;
    float dinvB = degB>0 ? 1.f/(float)degB : 0.f;
    a0.x=(a0.x+a1.x)*dinvA; a0.y=(a0.y+a1.y)*dinvA; a0.z=(a0.z+a1.z)*dinvA; a0.w=(a0.w+a1.w)*dinvA;
    c0.x=(c0.x+c1.x)*dinvB; c0.y=(c0.y+c1.y)*dinvB; c0.z=(c0.z+c1.z)*dinvB; c0.w=(c0.w+c1.w)*dinvB;
    if (lane==0 && eA<NE) tb[eA] = tsA*dinvA;
    if (lane==0 && eB<NE) tb[eB] = tsB*dinvB;
    ushort4 oA, oB;
    oA.x=f2bf(a0.x); oA.y=f2bf(a0.y); oA.z=f2bf(a0.z); oA.w=f2bf(a0.w);
    oB.x=f2bf(c0.x); oB.y=f2bf(c0.y); oB.z=f2bf(c0.z); oB.w=f2bf(c0.w);
    *reinterpret_cast<ushort4*>(&lds[rA][lane*4]) = oA;
    *reinterpret_cast<ushort4*>(&lds[rB][lane*4]) = oB;
  }
  __syncthreads();

  int rr = lane & 15, kg = lane >> 4;
  f32x4 acc0={0,0,0,0}, acc1={0,0,0,0}, acc2={0,0,0,0}, acc3={0,0,0,0};
  #pragma unroll
  for (int s=0; s<8; ++s){
    bf16x8 a = *reinterpret_cast<bf16x8*>(&lds[rr][s*32 + kg*8]);
    const u16* wb = &Wh[(size_t)((w*4)*16 + rr)*256 + s*32 + kg*8];
    bf16x8 b0 = *reinterpret_cast<const bf16x8*>(wb);
    bf16x8 b1 = *reinterpret_cast<const bf16x8*>(wb + 16*256);
    bf16x8 b2 = *reinterpret_cast<const bf16x8*>(wb + 32*256);
    bf16x8 b3 = *reinterpret_cast<const bf16x8*>(wb + 48*256);
    acc0 = __builtin_amdgcn_mfma_f32_16x16x32_bf16(a, b0, acc0, 0,0,0);
    acc1 = __builtin_amdgcn_mfma_f32_16x16x32_bf16(a, b1, acc1, 0,0,0);
    acc2 = __builtin_amdgcn_mfma_f32_16x16x32_bf16(a, b2, acc2, 0,0,0);
    acc3 = __builtin_amdgcn_mfma_f32_16x16x32_bf16(a, b3, acc3, 0,0,0);
  }
  __syncthreads();
  #pragma unroll
  for (int reg=0; reg<4; ++reg){
    int row = kg*4 + reg;
    lds[row][(w*4+0)*16 + rr] = f2bf(acc0[reg]);
    lds[row][(w*4+1)*16 + rr] = f2bf(acc1[reg]);
    lds[row][(w*4+2)*16 + rr] = f2bf(acc2[reg]);
    lds[row][(w*4+3)*16 + rr] = f2bf(acc3[reg]);
  }
  __syncthreads();
  int orow = t>>4, oseg = t&15;
  int e = e0 + orow;
  if (e < NE){
    uint4 d0 = *reinterpret_cast<uint4*>(&lds[orow][oseg*16]);
    uint4 d1 = *reinterpret_cast<uint4*>(&lds[orow][oseg*16+8]);
    *reinterpret_cast<uint4*>(&Ue[(size_t)e*256 + oseg*16])     = d0;
    *reinterpret_cast<uint4*>(&Ue[(size_t)e*256 + oseg*16 + 8]) = d1;
  }
}

// ---- 6. out[v] = relu( dv_isqrt[v]*(sum Ue[e]) + dv_isqrt[v]*(sum tb[e])*b ) ----
__global__ __launch_bounds__(256) void k_zv(const int* __restrict__ dv_cnt, const u16* __restrict__ v_listP,
                    const ushort4* __restrict__ Ue4, const float* __restrict__ tb,
                    const float* __restrict__ dv_isqrt, const float4* __restrict__ b4,
                    float4* __restrict__ out4){
  int v = blockIdx.x*4 + (threadIdx.x>>6);
  if (v >= NV) return;
  int lane = threadIdx.x & 63;
  int deg = dv_cnt[v];
  int base = v*VSTRIDE;
  float4 a0 = make_float4(0,0,0,0), a1 = make_float4(0,0,0,0);
  float sb0 = 0.f, sb1 = 0.f;
  int m = 0;
  for (; m+8 <= deg; m += 8){
    int e0=v_listP[base+m+0], e1=v_listP[base+m+1], e2=v_listP[base+m+2], e3=v_listP[base+m+3];
    int e4=v_listP[base+m+4], e5=v_listP[base+m+5], e6=v_listP[base+m+6], e7=v_listP[base+m+7];
    ushort4 u0=Ue4[(e0<<6)+lane], u1=Ue4[(e1<<6)+lane], u2=Ue4[(e2<<6)+lane], u3=Ue4[(e3<<6)+lane];
    ushort4 u4=Ue4[(e4<<6)+lane], u5=Ue4[(e5<<6)+lane], u6=Ue4[(e6<<6)+lane], u7=Ue4[(e7<<6)+lane];
    acc4(a0,u0); acc4(a1,u1); acc4(a0,u2); acc4(a1,u3);
    acc4(a0,u4); acc4(a1,u5); acc4(a0,u6); acc4(a1,u7);
    sb0 += tb[e0]+tb[e2]+tb[e4]+tb[e6];
    sb1 += tb[e1]+tb[e3]+tb[e5]+tb[e7];
  }
  for (; m<deg; ++m){
    int e = v_listP[base+m];
    ushort4 u = Ue4[(e<<6)+lane];
    acc4(a0,u);
    sb0 += tb[e];
  }
  float4 acc;
  acc.x=a0.x+a1.x; acc.y=a0.y+a1.y; acc.z=a0.z+a1.z; acc.w=a0.w+a1.w;
  float w = dv_isqrt[v];
  float sw = (sb0+sb1)*w;
  float4 bb = b4[lane];
  float4 o;
  o.x = fmaxf(0.f, fmaf(sw, bb.x, acc.x*w));
  o.y = fmaxf(0.f, fmaf(sw, bb.y, acc.y*w));
  o.z = fmaxf(0.f, fmaf(sw, bb.z, acc.z*w));
  o.w = fmaxf(0.f, fmaf(sw, bb.w, acc.w*w));
  out4[(v<<6)+lane] = o;
}

extern "C" void kernel_launch(void* const* d_in, const int* in_sizes, int n_in,
                              void* d_out, int out_size, void* d_ws, size_t ws_size,
                              hipStream_t stream) {
  const float* X = (const float*)d_in[0];
  const float* W = (const float*)d_in[1];
  const float* b = (const float*)d_in[2];
  const int* v_idx = (const int*)d_in[3];
  const int* e_idx = (const int*)d_in[4];
  float* out = (float*)d_out;

  char* p = (char*)d_ws;
  auto alloc = [&](size_t bytes)->void*{
    void* r = (void*)p; p += (bytes + 255) & ~(size_t)255; return r;
  };
  int* dv_cnt     = (int*)alloc((size_t)NV*4);
  int* de_cnt     = (int*)alloc((size_t)NE*4);
  float* dv_isqrt = (float*)alloc((size_t)NV*4);
  float* tb       = (float*)alloc((size_t)NE*4);
  int* e_listP    = (int*)alloc((size_t)NE*ESTRIDE*4);   // 12.8 MB
  u16* v_listP    = (u16*)alloc((size_t)NV*VSTRIDE*2);   // 9.6 MB
  u16* Wh         = (u16*)alloc((size_t)CH*CH*2);        // 128 KB
  u16* Ue         = (u16*)alloc((size_t)NE*CH*2);        // 12.8 MB
  u16* Xs         = (u16*)d_out;      // staging inside d_out (dead before k_zv writes)

  hipMemsetAsync(dv_cnt, 0, (size_t)NV*4, stream);
  hipMemsetAsync(de_cnt, 0, (size_t)NE*4, stream);

  k_build<<<1024,256,0,stream>>>(v_idx,e_idx,dv_cnt,de_cnt,v_listP,e_listP);
  k_dvis<<<(NV+255)/256,256,0,stream>>>(dv_cnt, dv_isqrt);
  k_xs<<<(NV*64)/256,256,0,stream>>>((const float4*)X, dv_isqrt, (ushort4*)Xs);
  k_wh<<<dim3(16,16),dim3(16,16),0,stream>>>(W, Wh);
  k_tegemm<<<(NE+15)/16,256,0,stream>>>(de_cnt,e_listP,(const ushort4*)Xs,dv_isqrt,Wh,tb,Ue);
  k_zv<<<(NV+3)/4,256,0,stream>>>(dv_cnt,v_listP,(const ushort4*)Ue,tb,dv_isqrt,(const float4*)b,(float4*)out);
}

// Round 12
// 369.703 us; speedup vs baseline: 1.1877x; 1.1877x over previous
//
#include <hip/hip_runtime.h>
#include <hip/hip_bf16.h>

#define NV 100000
#define NE 25000
#define NNZ_ 1600000
#define CH 256
#define TS 4096                 // sort tile per block
#define NB_T 391                // ceil(NNZ/TS)
#define EBINS 196               // e>>7  (e<25000)
#define VBINS 196               // v>>9  (v<100000)
#define HTOT (196*NB_T)         // 76636
#define SEGCAP 9216             // segment cap: Poisson(8192) mean +11 sigma
#define LDSK 264

typedef unsigned int u32;
typedef unsigned short u16;
typedef __attribute__((ext_vector_type(8))) short bf16x8;
typedef __attribute__((ext_vector_type(4))) float f32x4;

__device__ __forceinline__ float bf2f(u16 u){ return __uint_as_float(((u32)u)<<16); }
__device__ __forceinline__ u16 f2bf(float f){ __hip_bfloat16 h = __float2bfloat16(f); return *reinterpret_cast<u16*>(&h); }
__device__ __forceinline__ void acc4(float4& a, ushort4 u){
  a.x += bf2f(u.x); a.y += bf2f(u.y); a.z += bf2f(u.z); a.w += bf2f(u.w);
}

// ---- 1a. per-block histograms over e>>7 and v>>9 (bin-major output) ----
__global__ __launch_bounds__(256) void k_hist(const int* __restrict__ v_idx, const int* __restrict__ e_idx,
                       int* __restrict__ histE, int* __restrict__ histV){
  __shared__ int hE[EBINS], hV[VBINS];
  for (int i=threadIdx.x;i<EBINS;i+=256) hE[i]=0;
  for (int i=threadIdx.x;i<VBINS;i+=256) hV[i]=0;
  __syncthreads();
  int i0 = blockIdx.x*TS;
  int n = min(TS, NNZ_-i0);
  for (int k=threadIdx.x;k<n;k+=256){
    int e = e_idx[i0+k], v = v_idx[i0+k];
    atomicAdd(&hE[e>>7],1);
    atomicAdd(&hV[v>>9],1);
  }
  __syncthreads();
  for (int i=threadIdx.x;i<EBINS;i+=256) histE[i*NB_T+blockIdx.x]=hE[i];
  for (int i=threadIdx.x;i<VBINS;i+=256) histV[i*NB_T+blockIdx.x]=hV[i];
}

// ---- 1b. multi-block exclusive scan (in-place safe: cnt may alias off) ----
__global__ void k_scanA(const int* cnt, int n, int* off, int* bsum){
  __shared__ int buf[1024];
  int i = blockIdx.x*1024 + threadIdx.x;
  int x = (i<n) ? cnt[i] : 0;
  buf[threadIdx.x] = x;
  __syncthreads();
  #pragma unroll
  for (int d=1; d<1024; d<<=1){
    int t = (threadIdx.x>=d) ? buf[threadIdx.x-d] : 0;
    __syncthreads();
    buf[threadIdx.x] += t;
    __syncthreads();
  }
  if (i<n) off[i] = buf[threadIdx.x] - x;
  if (threadIdx.x==1023) bsum[blockIdx.x] = buf[1023];
}

__global__ void k_scanB(int* bsum, int nb){
  __shared__ int buf[128];
  int x = (threadIdx.x<nb) ? bsum[threadIdx.x] : 0;
  buf[threadIdx.x] = x;
  __syncthreads();
  #pragma unroll
  for (int d=1; d<128; d<<=1){
    int t = (threadIdx.x>=d) ? buf[threadIdx.x-d] : 0;
    __syncthreads();
    buf[threadIdx.x] += t;
    __syncthreads();
  }
  if (threadIdx.x<nb) bsum[threadIdx.x] = buf[threadIdx.x] - x;
}

__global__ void k_scanC2(int* off, const int* __restrict__ bsum, int n){
  int i = blockIdx.x*blockDim.x + threadIdx.x;
  if (i<n) off[i] += bsum[i>>10];
}

// ---- 1c. scatter packed pairs to bucket-major tmp (runs of ~21 per bin/block) ----
__global__ __launch_bounds__(256) void k_scat(const int* __restrict__ v_idx, const int* __restrict__ e_idx,
                       const int* __restrict__ baseE, const int* __restrict__ baseV,
                       u32* __restrict__ tmpE, u32* __restrict__ tmpV){
  __shared__ int bE[EBINS], bV[VBINS], cE[EBINS], cV[VBINS];
  for (int i=threadIdx.x;i<EBINS;i+=256){ bE[i]=baseE[i*NB_T+blockIdx.x]; cE[i]=0; }
  for (int i=threadIdx.x;i<VBINS;i+=256){ bV[i]=baseV[i*NB_T+blockIdx.x]; cV[i]=0; }
  __syncthreads();
  int i0 = blockIdx.x*TS;
  int n = min(TS, NNZ_-i0);
  for (int k=threadIdx.x;k<n;k+=256){
    int e = e_idx[i0+k], v = v_idx[i0+k];
    int be = e>>7, bv = v>>9;
    int r  = atomicAdd(&cE[be],1);
    tmpE[bE[be]+r] = ((u32)e<<17) | (u32)v;
    int r2 = atomicAdd(&cV[bv],1);
    tmpV[bV[bv]+r2] = ((u32)v<<15) | (u32)e;
  }
}

// ---- 1d. within-segment sort by low bits -> real CSR (offsets + contiguous lists) ----
__global__ __launch_bounds__(256) void k_seg2e(const int* __restrict__ baseE, const u32* __restrict__ tmpE,
                        int* __restrict__ e_off, int* __restrict__ e_list){
  int seg = blockIdx.x;
  int s0 = baseE[seg*NB_T];
  int s1 = (seg+1<EBINS) ? baseE[(seg+1)*NB_T] : NNZ_;
  int len = s1 - s0;
  __shared__ u32 buf[SEGCAP];
  __shared__ int cnt[128], st[129];
  for (int i=threadIdx.x;i<128;i+=256) cnt[i]=0;
  __syncthreads();
  bool fit = (len <= SEGCAP);
  if (fit){
    for (int i=threadIdx.x;i<len;i+=256){ u32 p=tmpE[s0+i]; buf[i]=p; atomicAdd(&cnt[(p>>17)&127],1); }
  } else {
    for (int i=threadIdx.x;i<len;i+=256){ u32 p=tmpE[s0+i]; atomicAdd(&cnt[(p>>17)&127],1); }
  }
  __syncthreads();
  if (threadIdx.x==0){ int a=0; for (int i=0;i<128;i++){ st[i]=a; a+=cnt[i]; } st[128]=a; }
  __syncthreads();
  for (int i=threadIdx.x;i<128;i+=256){
    int e = seg*128 + i;
    if (e < NE) e_off[e] = s0 + st[i];
  }
  if (seg==EBINS-1 && threadIdx.x==0) e_off[NE] = NNZ_;
  for (int i=threadIdx.x;i<128;i+=256) cnt[i]=0;
  __syncthreads();
  if (fit){
    for (int i=threadIdx.x;i<len;i+=256){
      u32 p=buf[i]; int lb=(p>>17)&127; int r=atomicAdd(&cnt[lb],1);
      e_list[s0+st[lb]+r] = (int)(p & 0x1FFFFu);
    }
  } else {
    for (int i=threadIdx.x;i<len;i+=256){
      u32 p=tmpE[s0+i]; int lb=(p>>17)&127; int r=atomicAdd(&cnt[lb],1);
      e_list[s0+st[lb]+r] = (int)(p & 0x1FFFFu);
    }
  }
}

__global__ __launch_bounds__(256) void k_seg2v(const int* __restrict__ baseV, const u32* __restrict__ tmpV,
                        int* __restrict__ v_off, u16* __restrict__ v_list){
  int seg = blockIdx.x;
  int s0 = baseV[seg*NB_T];
  int s1 = (seg+1<VBINS) ? baseV[(seg+1)*NB_T] : NNZ_;
  int len = s1 - s0;
  __shared__ u32 buf[SEGCAP];
  __shared__ int cnt[512], st[513];
  for (int i=threadIdx.x;i<512;i+=256) cnt[i]=0;
  __syncthreads();
  bool fit = (len <= SEGCAP);
  if (fit){
    for (int i=threadIdx.x;i<len;i+=256){ u32 p=tmpV[s0+i]; buf[i]=p; atomicAdd(&cnt[(p>>15)&511],1); }
  } else {
    for (int i=threadIdx.x;i<len;i+=256){ u32 p=tmpV[s0+i]; atomicAdd(&cnt[(p>>15)&511],1); }
  }
  __syncthreads();
  if (threadIdx.x==0){ int a=0; for (int i=0;i<512;i++){ st[i]=a; a+=cnt[i]; } st[512]=a; }
  __syncthreads();
  for (int i=threadIdx.x;i<512;i+=256){
    int v = seg*512 + i;
    if (v < NV) v_off[v] = s0 + st[i];
  }
  if (seg==VBINS-1 && threadIdx.x==0) v_off[NV] = NNZ_;
  for (int i=threadIdx.x;i<512;i+=256) cnt[i]=0;
  __syncthreads();
  if (fit){
    for (int i=threadIdx.x;i<len;i+=256){
      u32 p=buf[i]; int lb=(p>>15)&511; int r=atomicAdd(&cnt[lb],1);
      v_list[s0+st[lb]+r] = (u16)(p & 0x7FFFu);
    }
  } else {
    for (int i=threadIdx.x;i<len;i+=256){
      u32 p=tmpV[s0+i]; int lb=(p>>15)&511; int r=atomicAdd(&cnt[lb],1);
      v_list[s0+st[lb]+r] = (u16)(p & 0x7FFFu);
    }
  }
}

// ---- 2. dv^-1/2 from CSR offsets ----
__global__ void k_dvis(const int* __restrict__ v_off, float* __restrict__ dv_isqrt){
  int v = blockIdx.x*blockDim.x + threadIdx.x;
  if (v < NV){ int d = v_off[v+1]-v_off[v]; dv_isqrt[v] = d>0 ? rsqrtf((float)d) : 0.f; }
}

// ---- 3. Xs = dv_isqrt * X, cast to bf16 ----
__global__ void k_xs(const float4* __restrict__ X4, const float* __restrict__ dv_isqrt,
                     ushort4* __restrict__ Xs4){
  int i = blockIdx.x*blockDim.x + threadIdx.x;
  int v = i >> 6;
  float w = dv_isqrt[v];
  float4 x = X4[i];
  ushort4 o;
  o.x = f2bf(x.x*w); o.y = f2bf(x.y*w); o.z = f2bf(x.z*w); o.w = f2bf(x.w*w);
  Xs4[i] = o;
}

// ---- 4. Wh[n][k] = bf16(W[k][n]) ----
__global__ void k_wh(const float* __restrict__ W, u16* __restrict__ Wh){
  __shared__ float tile[16][17];
  int bx=blockIdx.x, by=blockIdx.y;
  int tx=threadIdx.x, ty=threadIdx.y;
  tile[ty][tx] = W[(by*16+ty)*256 + bx*16+tx];
  __syncthreads();
  Wh[(bx*16+ty)*256 + by*16+tx] = f2bf(tile[tx][ty]);
}

// ---- 5. fused: gather 16-edge tile -> LDS bf16 -> MFMA @ Wh -> Ue bf16 (+tb) ----
__global__ __launch_bounds__(256) void k_tegemm(const int* __restrict__ e_off,
                     const int* __restrict__ e_list, const ushort4* __restrict__ Xs4,
                     const float* __restrict__ dv_isqrt, const u16* __restrict__ Wh,
                     float* __restrict__ tb, u16* __restrict__ Ue){
  __shared__ u16 lds[16][LDSK];
  int t = threadIdx.x, w = t>>6, lane = t&63;
  int e0 = blockIdx.x*16;

  for (int j=0;j<4;++j){
    int e = e0 + w*4 + j;
    int r = w*4 + j;
    float4 a0=make_float4(0,0,0,0), a1=make_float4(0,0,0,0);
    float ts = 0.f;
    if (e < NE){
      int beg = e_off[e], deg = e_off[e+1]-beg;
      int m = 0;
      for (; m+8 <= deg; m += 8){
        int v0=e_list[beg+m+0], v1=e_list[beg+m+1], v2=e_list[beg+m+2], v3=e_list[beg+m+3];
        int v4=e_list[beg+m+4], v5=e_list[beg+m+5], v6=e_list[beg+m+6], v7=e_list[beg+m+7];
        ushort4 u0=Xs4[(v0<<6)+lane], u1=Xs4[(v1<<6)+lane], u2=Xs4[(v2<<6)+lane], u3=Xs4[(v3<<6)+lane];
        ushort4 u4=Xs4[(v4<<6)+lane], u5=Xs4[(v5<<6)+lane], u6=Xs4[(v6<<6)+lane], u7=Xs4[(v7<<6)+lane];
        acc4(a0,u0); acc4(a1,u1); acc4(a0,u2); acc4(a1,u3);
        acc4(a0,u4); acc4(a1,u5); acc4(a0,u6); acc4(a1,u7);
        ts += dv_isqrt[v0]+dv_isqrt[v1]+dv_isqrt[v2]+dv_isqrt[v3]
            + dv_isqrt[v4]+dv_isqrt[v5]+dv_isqrt[v6]+dv_isqrt[v7];
      }
      for (; m<deg; ++m){
        int v = e_list[beg+m];
        ushort4 u = Xs4[(v<<6)+lane];
        acc4(a0,u);
        ts += dv_isqrt[v];
      }
      float dinv = deg>0 ? 1.f/(float)deg : 0.f;
      a0.x=(a0.x+a1.x)*dinv; a0.y=(a0.y+a1.y)*dinv; a0.z=(a0.z+a1.z)*dinv; a0.w=(a0.w+a1.w)*dinv;
      if (lane==0) tb[e] = ts*dinv;
    }
    ushort4 o;
    o.x=f2bf(a0.x); o.y=f2bf(a0.y); o.z=f2bf(a0.z); o.w=f2bf(a0.w);
    *reinterpret_cast<ushort4*>(&lds[r][lane*4]) = o;
  }
  __syncthreads();

  int rr = lane & 15, kg = lane >> 4;
  f32x4 acc0={0,0,0,0}, acc1={0,0,0,0}, acc2={0,0,0,0}, acc3={0,0,0,0};
  #pragma unroll
  for (int s=0; s<8; ++s){
    bf16x8 a = *reinterpret_cast<bf16x8*>(&lds[rr][s*32 + kg*8]);
    const u16* wb = &Wh[(size_t)((w*4)*16 + rr)*256 + s*32 + kg*8];
    bf16x8 b0 = *reinterpret_cast<const bf16x8*>(wb);
    bf16x8 b1 = *reinterpret_cast<const bf16x8*>(wb + 16*256);
    bf16x8 b2 = *reinterpret_cast<const bf16x8*>(wb + 32*256);
    bf16x8 b3 = *reinterpret_cast<const bf16x8*>(wb + 48*256);
    acc0 = __builtin_amdgcn_mfma_f32_16x16x32_bf16(a, b0, acc0, 0,0,0);
    acc1 = __builtin_amdgcn_mfma_f32_16x16x32_bf16(a, b1, acc1, 0,0,0);
    acc2 = __builtin_amdgcn_mfma_f32_16x16x32_bf16(a, b2, acc2, 0,0,0);
    acc3 = __builtin_amdgcn_mfma_f32_16x16x32_bf16(a, b3, acc3, 0,0,0);
  }
  __syncthreads();
  #pragma unroll
  for (int reg=0; reg<4; ++reg){
    int row = kg*4 + reg;
    lds[row][(w*4+0)*16 + rr] = f2bf(acc0[reg]);
    lds[row][(w*4+1)*16 + rr] = f2bf(acc1[reg]);
    lds[row][(w*4+2)*16 + rr] = f2bf(acc2[reg]);
    lds[row][(w*4+3)*16 + rr] = f2bf(acc3[reg]);
  }
  __syncthreads();
  int orow = t>>4, oseg = t&15;
  int e = e0 + orow;
  if (e < NE){
    uint4 d0 = *reinterpret_cast<uint4*>(&lds[orow][oseg*16]);
    uint4 d1 = *reinterpret_cast<uint4*>(&lds[orow][oseg*16+8]);
    *reinterpret_cast<uint4*>(&Ue[(size_t)e*256 + oseg*16])     = d0;
    *reinterpret_cast<uint4*>(&Ue[(size_t)e*256 + oseg*16 + 8]) = d1;
  }
}

// ---- 6. out[v] = relu( dv_isqrt[v]*(sum Ue[e]) + dv_isqrt[v]*(sum tb[e])*b ) ----
__global__ __launch_bounds__(256) void k_zv(const int* __restrict__ v_off, const u16* __restrict__ v_list,
                    const ushort4* __restrict__ Ue4, const float* __restrict__ tb,
                    const float* __restrict__ dv_isqrt, const float4* __restrict__ b4,
                    float4* __restrict__ out4){
  int v = blockIdx.x*4 + (threadIdx.x>>6);
  if (v >= NV) return;
  int lane = threadIdx.x & 63;
  int base = v_off[v];
  int deg = v_off[v+1] - base;
  float4 a0 = make_float4(0,0,0,0), a1 = make_float4(0,0,0,0);
  float sb0 = 0.f, sb1 = 0.f;
  int m = 0;
  for (; m+8 <= deg; m += 8){
    int e0=v_list[base+m+0], e1=v_list[base+m+1], e2=v_list[base+m+2], e3=v_list[base+m+3];
    int e4=v_list[base+m+4], e5=v_list[base+m+5], e6=v_list[base+m+6], e7=v_list[base+m+7];
    ushort4 u0=Ue4[(e0<<6)+lane], u1=Ue4[(e1<<6)+lane], u2=Ue4[(e2<<6)+lane], u3=Ue4[(e3<<6)+lane];
    ushort4 u4=Ue4[(e4<<6)+lane], u5=Ue4[(e5<<6)+lane], u6=Ue4[(e6<<6)+lane], u7=Ue4[(e7<<6)+lane];
    acc4(a0,u0); acc4(a1,u1); acc4(a0,u2); acc4(a1,u3);
    acc4(a0,u4); acc4(a1,u5); acc4(a0,u6); acc4(a1,u7);
    sb0 += tb[e0]+tb[e2]+tb[e4]+tb[e6];
    sb1 += tb[e1]+tb[e3]+tb[e5]+tb[e7];
  }
  for (; m<deg; ++m){
    int e = v_list[base+m];
    ushort4 u = Ue4[(e<<6)+lane];
    acc4(a0,u);
    sb0 += tb[e];
  }
  float4 acc;
  acc.x=a0.x+a1.x; acc.y=a0.y+a1.y; acc.z=a0.z+a1.z; acc.w=a0.w+a1.w;
  float w = dv_isqrt[v];
  float sw = (sb0+sb1)*w;
  float4 bb = b4[lane];
  float4 o;
  o.x = fmaxf(0.f, fmaf(sw, bb.x, acc.x*w));
  o.y = fmaxf(0.f, fmaf(sw, bb.y, acc.y*w));
  o.z = fmaxf(0.f, fmaf(sw, bb.z, acc.z*w));
  o.w = fmaxf(0.f, fmaf(sw, bb.w, acc.w*w));
  out4[(v<<6)+lane] = o;
}

extern "C" void kernel_launch(void* const* d_in, const int* in_sizes, int n_in,
                              void* d_out, int out_size, void* d_ws, size_t ws_size,
                              hipStream_t stream) {
  const float* X = (const float*)d_in[0];
  const float* W = (const float*)d_in[1];
  const float* b = (const float*)d_in[2];
  const int* v_idx = (const int*)d_in[3];
  const int* e_idx = (const int*)d_in[4];
  float* out = (float*)d_out;

  char* p = (char*)d_ws;
  auto alloc = [&](size_t bytes)->void*{
    void* r = (void*)p; p += (bytes + 255) & ~(size_t)255; return r;
  };
  int* histE      = (int*)alloc((size_t)HTOT*4);         // 307 KB (scanned in place)
  int* histV      = (int*)alloc((size_t)HTOT*4);         // 307 KB
  int* bsumE      = (int*)alloc(128*4);
  int* bsumV      = (int*)alloc(128*4);
  int* e_off      = (int*)alloc((size_t)(NE+1)*4);
  int* v_off      = (int*)alloc((size_t)(NV+1)*4);
  float* dv_isqrt = (float*)alloc((size_t)NV*4);
  float* tb       = (float*)alloc((size_t)NE*4);
  u32* tmpE       = (u32*)alloc((size_t)NNZ_*4);         // 6.4 MB  \ contiguous ->
  u32* tmpV       = (u32*)alloc((size_t)NNZ_*4);         // 6.4 MB  / Ue overlay (12.8 MB)
  int* e_list     = (int*)alloc((size_t)NNZ_*4);         // 6.4 MB
  u16* v_list     = (u16*)alloc((size_t)NNZ_*2);         // 3.2 MB
  u16* Wh         = (u16*)alloc((size_t)CH*CH*2);        // 128 KB
  u16* Ue         = (u16*)tmpE;     // overlay: tmp dead after seg2, Ue written by tegemm
  u16* Xs         = (u16*)d_out;    // staging inside d_out (dead before k_zv writes)

  const int nbS = (HTOT+1023)/1024;   // 75

  k_hist<<<NB_T,256,0,stream>>>(v_idx,e_idx,histE,histV);
  k_scanA<<<nbS,1024,0,stream>>>(histE,HTOT,histE,bsumE);
  k_scanA<<<nbS,1024,0,stream>>>(histV,HTOT,histV,bsumV);
  k_scanB<<<1,128,0,stream>>>(bsumE,nbS);
  k_scanB<<<1,128,0,stream>>>(bsumV,nbS);
  k_scanC2<<<(HTOT+255)/256,256,0,stream>>>(histE,bsumE,HTOT);
  k_scanC2<<<(HTOT+255)/256,256,0,stream>>>(histV,bsumV,HTOT);
  k_scat<<<NB_T,256,0,stream>>>(v_idx,e_idx,histE,histV,tmpE,tmpV);
  k_seg2e<<<EBINS,256,0,stream>>>(histE,tmpE,e_off,e_list);
  k_seg2v<<<VBINS,256,0,stream>>>(histV,tmpV,v_off,v_list);

  k_dvis<<<(NV+255)/256,256,0,stream>>>(v_off, dv_isqrt);
  k_xs<<<(NV*64)/256,256,0,stream>>>((const float4*)X, dv_isqrt, (ushort4*)Xs);
  k_wh<<<dim3(16,16),dim3(16,16),0,stream>>>(W, Wh);
  k_tegemm<<<(NE+15)/16,256,0,stream>>>(e_off,e_list,(const ushort4*)Xs,dv_isqrt,Wh,tb,Ue);
  k_zv<<<(NV+3)/4,256,0,stream>>>(v_off,v_list,(const ushort4*)Ue,tb,dv_isqrt,(const float4*)b,(float4*)out);
}